// Round 2
// baseline (385.850 us; speedup 1.0000x reference)
//
#include <hip/hip_runtime.h>
#include <math.h>

// ---------------------------------------------------------------------------
// LightweightEncoder, round 2: fused tiled implementation.
//  k_mega     : per 64x64 x_init tile (LDS): sample conv (x), ctx L0 (h0),
//               pool1 (p1), pool2 (p2). sigma via closed-form eig + Newton.
//  k_ctx_tile : tiled ctx conv (L1,L2,L3); L2 also writes f1=feat(h2),
//               L3 writes only f2=feat(h3). L3 zeroes acc.
//  k_final    : select + soft VQ (+__expf), cond counts + all 3 histograms
//               (ballot-based, mask1/mask2 folded in).
//  k_finalize : scalars.
// ---------------------------------------------------------------------------

#define SENT -1e30f   // OOB sentinel: bn_g>0 so relu(inv*SENT+bb)==0 (pad-after-bnrelu)

__device__ __forceinline__ float featf(float h) { return 0.5f * (tanhf(h) + 1.0f); }

// ---------------------------------------------------------------------------
// K0: mega kernel. grid = 8 batches x 16 x 16 tiles, block 256.
// ---------------------------------------------------------------------------
__global__ __launch_bounds__(256) void k_mega(
    const float* __restrict__ xin,
    const float* __restrict__ sw, const float* __restrict__ sb,
    const float* __restrict__ ctxw, const float* __restrict__ ctxb,
    const float* __restrict__ bng, const float* __restrict__ bnb,
    const float* __restrict__ p1w, const float* __restrict__ p1b,
    const float* __restrict__ p2w, const float* __restrict__ p2b,
    float* __restrict__ outX, float* __restrict__ outH0,
    float* __restrict__ outP1, float* __restrict__ outP2)
{
    __shared__ float sx[3][66][68];     // input tile rows -1..63, cols -1..64 (lc 0..64 used)
    __shared__ float sxo[3][16][16];    // x tile
    __shared__ float sp1[3][8][8];      // p1 tile
    __shared__ float cw[81], cb[3], cinv[3], cbb[3];
    __shared__ float swt[144], ssb[3];
    __shared__ float w1[36], b1[3], w2[36], b2[3];
    __shared__ float s_invsig;

    int t = threadIdx.x;
    int bid = blockIdx.x;
    int bx = bid & 15, by = (bid >> 4) & 15, b = bid >> 8;

    if (t < 81)  cw[t]  = ctxw[t];
    if (t < 144) swt[t] = sw[t];
    if (t < 36)  { w1[t] = p1w[t]; w2[t] = p2w[t]; }
    if (t < 3) {
        cb[t] = ctxb[t]; cinv[t] = bng[t] / sqrtf(1.001f); cbb[t] = bnb[t];
        ssb[t] = sb[t]; b1[t] = p1b[t]; b2[t] = p2b[t];
    }

    // ---- stage 65x65 input tile per channel (float4 core + left halo) ----
    int q = t & 15, lrb = t >> 4;
    int gc0 = bx * 64;
    for (int c = 0; c < 3; c++) {
        const float* base = xin + ((size_t)(b * 3 + c) << 20);
        for (int j = 0; j < 5; j++) {
            int lr = lrb + 16 * j;
            if (lr < 65) {
                int gr = by * 64 - 1 + lr;
                bool rowOK = (gr >= 0) && (gr < 1024);
                float4 v;
                if (rowOK) v = *(const float4*)(base + (size_t)gr * 1024 + gc0 + 4 * q);
                else { v.x = SENT; v.y = SENT; v.z = SENT; v.w = SENT; }
                float* dst = &sx[c][lr][1 + 4 * q];
                dst[0] = v.x; dst[1] = v.y; dst[2] = v.z; dst[3] = v.w;
                if (q == 0) {
                    int gc = gc0 - 1;
                    sx[c][lr][0] = (rowOK && gc >= 0) ? base[(size_t)gr * 1024 + gc] : SENT;
                }
            }
        }
    }

    // ---- sigma: largest singular value of sample_w (3x48), per-block lane 0 ----
    if (t == 0) {
        double G00=0,G01=0,G02=0,G11=0,G12=0,G22=0;
        for (int k = 0; k < 48; k++) {
            double a0 = sw[k], a1 = sw[48 + k], a2 = sw[96 + k];
            G00 += a0*a0; G01 += a0*a1; G02 += a0*a2;
            G11 += a1*a1; G12 += a1*a2; G22 += a2*a2;
        }
        double c2 = G00 + G11 + G22;
        double c1 = G00*G11 - G01*G01 + G00*G22 - G02*G02 + G11*G22 - G12*G12;
        double c0 = G00*(G11*G22 - G12*G12) - G01*(G01*G22 - G12*G02)
                  + G02*(G01*G12 - G11*G02);
        // float closed-form initial guess for largest eigenvalue
        float qf = (float)(c2 / 3.0);
        float p1f = (float)(G01*G01 + G02*G02 + G12*G12);
        float p2f = (float)((G00-qf)*(G00-qf) + (G11-qf)*(G11-qf) + (G22-qf)*(G22-qf))
                  + 2.0f * p1f;
        float lam;
        if (p2f < 1e-30f) lam = qf;
        else {
            float p = sqrtf(p2f / 6.0f);
            double pd = (double)p;
            double B00=(G00-qf)/pd, B01=G01/pd, B02=G02/pd;
            double B11=(G11-qf)/pd, B12=G12/pd, B22=(G22-qf)/pd;
            double detB = B00*(B11*B22 - B12*B12) - B01*(B01*B22 - B12*B02)
                        + B02*(B01*B12 - B11*B02);
            float r = (float)(detB * 0.5);
            r = fminf(1.0f, fmaxf(-1.0f, r));
            lam = qf + 2.0f * p * cosf(acosf(r) / 3.0f);
        }
        double L = (double)lam;   // Newton polish on char poly, exact to ~1e-14
        for (int it = 0; it < 3; it++) {
            double pv = ((L - c2) * L + c1) * L - c0;
            double dv = (3.0 * L - 2.0 * c2) * L + c1;
            if (fabs(dv) > 1e-300) L -= pv / dv;
        }
        s_invsig = (float)(1.0 / sqrt(L));
    }
    __syncthreads();

    // ---- ctx L0: 32x32 output tile, 4 px/thread ----
    {
        int ox = t & 31, oyb = t >> 5;
        for (int i = 0; i < 4; i++) {
            int oy = oyb + 8 * i;
            float a0 = cb[0], a1 = cb[1], a2 = cb[2];
            #pragma unroll
            for (int c = 0; c < 3; c++) {
                float inv = cinv[c], bb = cbb[c];
                #pragma unroll
                for (int kh = 0; kh < 3; kh++) {
                    #pragma unroll
                    for (int kw = 0; kw < 3; kw++) {
                        float v = sx[c][2 * oy + kh][2 * ox + kw];
                        v = fmaxf(fmaf(inv, v, bb), 0.0f);
                        int wi = c * 9 + kh * 3 + kw;
                        a0 += cw[wi] * v; a1 += cw[27 + wi] * v; a2 += cw[54 + wi] * v;
                    }
                }
            }
            size_t o = ((size_t)(b * 3)) * 262144 + (size_t)(by * 32 + oy) * 512 + bx * 32 + ox;
            outH0[o] = a0; outH0[o + 262144] = a1; outH0[o + 524288] = a2;
        }
    }

    // ---- sample conv: 16x16 x tile, 1 px/thread ----
    float x0, x1, x2;
    {
        int xl = t & 15, yl = t >> 4;
        float s0 = 0.f, s1 = 0.f, s2 = 0.f;
        #pragma unroll
        for (int c = 0; c < 3; c++) {
            #pragma unroll
            for (int kh = 0; kh < 4; kh++) {
                const float* r  = &sx[c][1 + 4 * yl + kh][1 + 4 * xl];
                const float* w0 = &swt[(0 * 3 + c) * 16 + kh * 4];
                const float* w1p= &swt[(1 * 3 + c) * 16 + kh * 4];
                const float* w2p= &swt[(2 * 3 + c) * 16 + kh * 4];
                #pragma unroll
                for (int kw = 0; kw < 4; kw++) {
                    float v = r[kw];
                    s0 += w0[kw] * v; s1 += w1p[kw] * v; s2 += w2p[kw] * v;
                }
            }
        }
        float isig = s_invsig;
        x0 = fmaf(s0, isig, ssb[0]);
        x1 = fmaf(s1, isig, ssb[1]);
        x2 = fmaf(s2, isig, ssb[2]);
        size_t o = ((size_t)(b * 3)) * 65536 + (size_t)(by * 16 + yl) * 256 + bx * 16 + xl;
        outX[o] = x0; outX[o + 65536] = x1; outX[o + 131072] = x2;
        sxo[0][yl][xl] = x0; sxo[1][yl][xl] = x1; sxo[2][yl][xl] = x2;
    }
    __syncthreads();

    // ---- pool1: 8x8 tile ----
    if (t < 64) {
        int px = t & 7, py = t >> 3;
        float a0 = b1[0], a1 = b1[1], a2 = b1[2];
        #pragma unroll
        for (int c = 0; c < 3; c++)
            #pragma unroll
            for (int kh = 0; kh < 2; kh++)
                #pragma unroll
                for (int kw = 0; kw < 2; kw++) {
                    float v = sxo[c][2 * py + kh][2 * px + kw];
                    int wi = c * 4 + kh * 2 + kw;
                    a0 += w1[wi] * v; a1 += w1[12 + wi] * v; a2 += w1[24 + wi] * v;
                }
        size_t o = ((size_t)(b * 3)) * 16384 + (size_t)(by * 8 + py) * 128 + bx * 8 + px;
        outP1[o] = a0; outP1[o + 16384] = a1; outP1[o + 32768] = a2;
        sp1[0][py][px] = a0; sp1[1][py][px] = a1; sp1[2][py][px] = a2;
    }
    __syncthreads();

    // ---- pool2: 4x4 tile ----
    if (t < 16) {
        int px = t & 3, py = t >> 2;
        float a0 = b2[0], a1 = b2[1], a2 = b2[2];
        #pragma unroll
        for (int c = 0; c < 3; c++)
            #pragma unroll
            for (int kh = 0; kh < 2; kh++)
                #pragma unroll
                for (int kw = 0; kw < 2; kw++) {
                    float v = sp1[c][2 * py + kh][2 * px + kw];
                    int wi = c * 4 + kh * 2 + kw;
                    a0 += w2[wi] * v; a1 += w2[12 + wi] * v; a2 += w2[24 + wi] * v;
                }
        size_t o = ((size_t)(b * 3)) * 4096 + (size_t)(by * 4 + py) * 64 + bx * 4 + px;
        outP2[o] = a0; outP2[o + 4096] = a1; outP2[o + 8192] = a2;
    }
}

// ---------------------------------------------------------------------------
// K1: tiled ctx conv (stride-2 3x3, pad-after-bnrelu). 64x64 in -> 32x32 out.
// grid = 8 * tps * tps blocks (tps = S/64). Optionally writes feat buffer,
// optionally zeroes acc (block 0).
// ---------------------------------------------------------------------------
__global__ __launch_bounds__(256) void k_ctx_tile(
    const float* __restrict__ in, float* __restrict__ outH, float* __restrict__ outF,
    const float* __restrict__ w, const float* __restrict__ bias,
    const float* __restrict__ bng, const float* __restrict__ bnb,
    int S, int tpsbits, int* __restrict__ accZero)
{
    __shared__ float sx[3][66][68];
    __shared__ float cw[81], cb[3], cinv[3], cbb[3];
    int t = threadIdx.x, bid = blockIdx.x;
    int tps = 1 << tpsbits;
    int tx = bid & (tps - 1), ty = (bid >> tpsbits) & (tps - 1), b = bid >> (2 * tpsbits);

    if (accZero && bid == 0 && t < 11) accZero[t] = 0;
    if (t < 81) cw[t] = w[t];
    if (t < 3) { cb[t] = bias[t]; cinv[t] = bng[t] / sqrtf(1.001f); cbb[t] = bnb[t]; }

    int q = t & 15, lrb = t >> 4;
    int gc0 = tx * 64;
    for (int c = 0; c < 3; c++) {
        const float* base = in + (size_t)(b * 3 + c) * S * S;
        for (int j = 0; j < 5; j++) {
            int lr = lrb + 16 * j;
            if (lr < 65) {
                int gr = ty * 64 - 1 + lr;
                bool rowOK = (gr >= 0) && (gr < S);
                float4 v;
                if (rowOK) v = *(const float4*)(base + (size_t)gr * S + gc0 + 4 * q);
                else { v.x = SENT; v.y = SENT; v.z = SENT; v.w = SENT; }
                float* dst = &sx[c][lr][1 + 4 * q];
                dst[0] = v.x; dst[1] = v.y; dst[2] = v.z; dst[3] = v.w;
                if (q == 0) {
                    int gc = gc0 - 1;
                    sx[c][lr][0] = (rowOK && gc >= 0) ? base[(size_t)gr * S + gc] : SENT;
                }
            }
        }
    }
    __syncthreads();

    int So = S >> 1;
    size_t os = (size_t)So * So;
    int ox = t & 31, oyb = t >> 5;
    for (int i = 0; i < 4; i++) {
        int oy = oyb + 8 * i;
        float a0 = cb[0], a1 = cb[1], a2 = cb[2];
        #pragma unroll
        for (int c = 0; c < 3; c++) {
            float inv = cinv[c], bb = cbb[c];
            #pragma unroll
            for (int kh = 0; kh < 3; kh++) {
                #pragma unroll
                for (int kw = 0; kw < 3; kw++) {
                    float v = sx[c][2 * oy + kh][2 * ox + kw];
                    v = fmaxf(fmaf(inv, v, bb), 0.0f);
                    int wi = c * 9 + kh * 3 + kw;
                    a0 += cw[wi] * v; a1 += cw[27 + wi] * v; a2 += cw[54 + wi] * v;
                }
            }
        }
        size_t o = (size_t)(b * 3) * os + (size_t)(ty * 32 + oy) * So + tx * 32 + ox;
        if (outH) { outH[o] = a0; outH[o + os] = a1; outH[o + 2 * os] = a2; }
        if (outF) { outF[o] = featf(a0); outF[o + os] = featf(a1); outF[o + 2 * os] = featf(a2); }
    }
}

// ---------------------------------------------------------------------------
// K2: final select + soft VQ + cond counts + all 3 histograms (ballot-based).
// grid 2048 x 256, one 256-res pixel per thread.
// ---------------------------------------------------------------------------
__device__ __forceinline__ int argmin8(float v, const float* sc) {
    float best = 1e30f; int ki = 0;
    #pragma unroll
    for (int k = 0; k < 8; k++) {
        float df = v - sc[k]; float dk = df * df;
        if (dk < best) { best = dk; ki = k; }
    }
    return ki;
}

__global__ __launch_bounds__(256) void k_final(
    const float* __restrict__ x, const float* __restrict__ f1,
    const float* __restrict__ f2, const float* __restrict__ p1,
    const float* __restrict__ p2, const float* __restrict__ thresh,
    const float* __restrict__ centers, float* __restrict__ out,
    int* __restrict__ acc)
{
    __shared__ float sc[8];
    __shared__ int sh[11];
    int t = threadIdx.x;
    if (t < 8) sc[t] = centers[t];
    if (t < 11) sh[t] = 0;
    __syncthreads();
    float th1 = thresh[0], th2 = thresh[1];
    int gid = blockIdx.x * 256 + t;
    int xc = gid & 255, y = (gid >> 8) & 255, b = gid >> 16;
    int i2 = ((y >> 1) << 7) + (xc >> 1);
    int i4 = ((y >> 2) << 6) + (xc >> 2);
    int lane = t & 63;
    bool doM1 = ((y & 1) == 0) && ((xc & 1) == 0);
    bool doM2 = ((y & 3) == 0) && ((xc & 3) == 0);
    int c0n = 0, c1n = 0, c2n = 0;

    for (int c = 0; c < 3; c++) {
        int pc = b * 3 + c;
        float f1v = f1[(size_t)pc * 16384 + i2];
        float f2v = f2[(size_t)pc * 4096 + i4];
        float p1v = p1[(size_t)pc * 16384 + i2];
        float p2v = p2[(size_t)pc * 4096 + i4];
        float xv  = x[(size_t)pc * 65536 + (y << 8) + xc];
        bool cond2 = f2v < th2;
        bool cond1 = (!cond2) && (f1v < th1);
        bool cond0 = !(cond1 || cond2);
        float xq = cond2 ? p2v : (cond1 ? p1v : xv);

        // soft VQ (max-subtracted softmax over -d)
        float d[8]; float dmin = 1e30f;
        #pragma unroll
        for (int k = 0; k < 8; k++) { float df = xq - sc[k]; d[k] = df * df; dmin = fminf(dmin, d[k]); }
        float se = 0.f, sn = 0.f;
        #pragma unroll
        for (int k = 0; k < 8; k++) { float e = __expf(dmin - d[k]); se += e; sn += sc[k] * e; }
        out[(size_t)pc * 65536 + (y << 8) + xc] = sn / se;

        c0n += cond0; c1n += cond1; c2n += cond2;

        // histogram contributions
        int k0 = argmin8(xv, sc);
        int k1 = argmin8(p1v, sc);
        int k2 = argmin8(p2v, sc);
        bool h0p = cond0;
        bool h1p = doM1 && (f2v >= th2) && (f1v < th1);
        bool h2p = doM2 && cond2;
        #pragma unroll
        for (int k = 0; k < 8; k++) {
            unsigned long long m0 = __ballot(h0p && (k0 == k));
            unsigned long long m1 = __ballot(h1p && (k1 == k));
            unsigned long long m2 = __ballot(h2p && (k2 == k));
            if (lane == 0) {
                int add = (int)(__popcll(m0) + __popcll(m1) + __popcll(m2));
                if (add) atomicAdd(&sh[k], add);
            }
        }
    }
    // wave-reduce cond counts
    for (int off = 32; off > 0; off >>= 1) {
        c0n += __shfl_down(c0n, off);
        c1n += __shfl_down(c1n, off);
        c2n += __shfl_down(c2n, off);
    }
    if (lane == 0) { atomicAdd(&sh[8], c0n); atomicAdd(&sh[9], c1n); atomicAdd(&sh[10], c2n); }
    __syncthreads();
    if (t < 11) { int v = sh[t]; if (v) atomicAdd(&acc[t], v); }
}

// K3: finalize scalars
__global__ void k_finalize(const int* __restrict__ acc, float* __restrict__ out2) {
    if (threadIdx.x != 0 || blockIdx.x != 0) return;
    float cnt0 = (float)acc[8], cnt1 = (float)acc[9], cnt2 = (float)acc[10];
    float esti = cnt0 + cnt1 / 4.0f + cnt2 / 16.0f;
    float cr = (1.0f / 16.0f) * esti / (256.0f * 256.0f * 3.0f * 8.0f);
    float cs[8];
    float tot = 0.0f;
    for (int k = 0; k < 8; k++) { cs[k] = (float)acc[k]; tot += cs[k]; }
    float mean = 0.0f;
    for (int k = 0; k < 8; k++) { cs[k] /= tot; mean += cs[k]; }
    mean /= 8.0f;
    float var = 0.0f;
    for (int k = 0; k < 8; k++) { float df = cs[k] - mean; var += df * df; }
    var /= 7.0f;
    out2[0] = cr;
    out2[1] = sqrtf(var);
}

extern "C" void kernel_launch(void* const* d_in, const int* in_sizes, int n_in,
                              void* d_out, int out_size, void* d_ws, size_t ws_size,
                              hipStream_t stream) {
    const float* x_init   = (const float*)d_in[0];
    const float* thresh   = (const float*)d_in[1];
    const float* sample_w = (const float*)d_in[2];
    const float* sample_b = (const float*)d_in[3];
    const float* centers  = (const float*)d_in[4];
    const float* pool1_w  = (const float*)d_in[5];
    const float* pool1_b  = (const float*)d_in[6];
    const float* pool2_w  = (const float*)d_in[7];
    const float* pool2_b  = (const float*)d_in[8];
    const float* ctx_w    = (const float*)d_in[9];
    const float* ctx_b    = (const float*)d_in[10];
    const float* bn_g     = (const float*)d_in[11];
    const float* bn_b     = (const float*)d_in[12];
    float* out = (float*)d_out;

    float* wsf   = (float*)d_ws;
    int*   acc   = (int*)(wsf + 256);
    float* bufX  = wsf + 512;                  // [8,3,256,256]
    float* bufH0 = bufX  + 1572864;            // [8,3,512,512]
    float* bufH1 = bufH0 + 6291456;            // [8,3,256,256]
    float* bufH2 = bufH1 + 1572864;            // [8,3,128,128]
    float* bufP1 = bufH2 + 393216;             // [8,3,128,128]
    float* bufP2 = bufP1 + 393216;             // [8,3,64,64]
    float* bufF1 = bufP2 + 98304;              // [8,3,128,128]
    float* bufF2 = bufF1 + 393216;             // [8,3,64,64]

    k_mega<<<2048, 256, 0, stream>>>(x_init, sample_w, sample_b,
                                     ctx_w, ctx_b, bn_g, bn_b,
                                     pool1_w, pool1_b, pool2_w, pool2_b,
                                     bufX, bufH0, bufP1, bufP2);
    k_ctx_tile<<<512, 256, 0, stream>>>(bufH0, bufH1, nullptr,
                                        ctx_w + 81,  ctx_b + 3, bn_g + 3, bn_b + 3,
                                        512, 3, nullptr);
    k_ctx_tile<<<128, 256, 0, stream>>>(bufH1, bufH2, bufF1,
                                        ctx_w + 162, ctx_b + 6, bn_g + 6, bn_b + 6,
                                        256, 2, nullptr);
    k_ctx_tile<<<32, 256, 0, stream>>>(bufH2, nullptr, bufF2,
                                       ctx_w + 243, ctx_b + 9, bn_g + 9, bn_b + 9,
                                       128, 1, acc);
    k_final<<<2048, 256, 0, stream>>>(bufX, bufF1, bufF2, bufP1, bufP2,
                                      thresh, centers, out, acc);
    k_finalize<<<1, 1, 0, stream>>>(acc, out + 1572864);
}

// Round 3
// 255.605 us; speedup vs baseline: 1.5096x; 1.5096x over previous
//
#include <hip/hip_runtime.h>
#include <math.h>

// ---------------------------------------------------------------------------
// LightweightEncoder, round 3: thin-band fused kernels (occupancy-first).
//  k_sigma_scale : 1 block; exact sigma (Gram 3x3 closed-form eig, double),
//                  scaled weights -> ws, zero acc.
//  k_band_l0     : per 64x16 x_init band (13.7 KB LDS): ctx L0 (h0),
//                  sample conv (x), pool1 (p1), pool2 (p2).
//  k_band_ctx    : per 64x16 band ctx conv (L1,L2,L3); L2 writes h2+f1,
//                  L3 writes f2.
//  k_final       : select + soft VQ + cond counts + 3 histograms (ballot).
//  k_finalize    : scalars.
// ---------------------------------------------------------------------------

#define SENT -1e30f      // OOB sentinel: relu(inv*SENT+bb)==0 (pad-after-bnrelu)
#define BSTR 67          // LDS band row stride (odd -> <=2-way bank aliasing)
#define BCH  (17 * BSTR) // per-channel band size (17 rows)

__device__ __forceinline__ float featf(float h) { return 0.5f * (tanhf(h) + 1.0f); }

// ---------------------------------------------------------------------------
// K0: sigma + weight scale + acc zero (single block)
// ---------------------------------------------------------------------------
__global__ void k_sigma_scale(const float* __restrict__ sw,
                              float* __restrict__ w_scaled,
                              int* __restrict__ acc) {
    __shared__ float s_sigma;
    int t = threadIdx.x;
    if (t == 0) {
        double G[3][3];
        for (int i = 0; i < 3; i++)
            for (int j = 0; j < 3; j++) {
                double s = 0.0;
                for (int k = 0; k < 48; k++)
                    s += (double)sw[i * 48 + k] * (double)sw[j * 48 + k];
                G[i][j] = s;
            }
        double p1 = G[0][1]*G[0][1] + G[0][2]*G[0][2] + G[1][2]*G[1][2];
        double q  = (G[0][0] + G[1][1] + G[2][2]) / 3.0;
        double p2 = (G[0][0]-q)*(G[0][0]-q) + (G[1][1]-q)*(G[1][1]-q)
                  + (G[2][2]-q)*(G[2][2]-q) + 2.0 * p1;
        double eig;
        if (p2 < 1e-30) {
            eig = q;
        } else {
            double p = sqrt(p2 / 6.0);
            double B[3][3];
            for (int i = 0; i < 3; i++)
                for (int j = 0; j < 3; j++)
                    B[i][j] = (G[i][j] - (i == j ? q : 0.0)) / p;
            double detB = B[0][0]*(B[1][1]*B[2][2]-B[1][2]*B[2][1])
                        - B[0][1]*(B[1][0]*B[2][2]-B[1][2]*B[2][0])
                        + B[0][2]*(B[1][0]*B[2][1]-B[1][1]*B[2][0]);
            double r = detB / 2.0;
            r = r < -1.0 ? -1.0 : (r > 1.0 ? 1.0 : r);
            double phi = acos(r) / 3.0;
            eig = q + 2.0 * p * cos(phi);
        }
        s_sigma = (float)sqrt(eig);
    }
    __syncthreads();
    float sig = s_sigma;
    for (int i = t; i < 144; i += blockDim.x) w_scaled[i] = sw[i] / sig;
    if (t < 11) acc[t] = 0;
}

// ---------------------------------------------------------------------------
// helper: stage a 17 x 66 (halo'd) band of one image into LDS
// ---------------------------------------------------------------------------
__device__ __forceinline__ void stage_band(const float* __restrict__ base,
                                           float* __restrict__ L,
                                           int gr0, int gc0, int S, int t) {
    int q = t & 15, r = t >> 4;      // r = 0..15
    {
        int gr = gr0 + r;
        float4 v;
        if (gr >= 0 && gr < S) v = *(const float4*)(base + (size_t)gr * S + gc0 + 4 * q);
        else { v.x = SENT; v.y = SENT; v.z = SENT; v.w = SENT; }
        float* d = &L[r * BSTR + 1 + 4 * q];
        d[0] = v.x; d[1] = v.y; d[2] = v.z; d[3] = v.w;
    }
    if (r == 0) {                    // row lr = 16 (gr0+16 >= 15 always >= 0)
        int gr = gr0 + 16;
        float4 v;
        if (gr < S) v = *(const float4*)(base + (size_t)gr * S + gc0 + 4 * q);
        else { v.x = SENT; v.y = SENT; v.z = SENT; v.w = SENT; }
        float* d = &L[16 * BSTR + 1 + 4 * q];
        d[0] = v.x; d[1] = v.y; d[2] = v.z; d[3] = v.w;
    }
    if (t >= 64 && t < 81) {         // left halo col (LDS col 0, global gc0-1)
        int lr = t - 64;
        int gr = gr0 + lr, gc = gc0 - 1;
        L[lr * BSTR] = (gr >= 0 && gr < S && gc >= 0) ? base[(size_t)gr * S + gc] : SENT;
    }
    if (t >= 96 && t < 113) {        // right halo col (LDS col 65, global gc0+64)
        int lr = t - 96;
        int gr = gr0 + lr, gc = gc0 + 64;
        L[lr * BSTR + 65] = (gr >= 0 && gr < S && gc < S) ? base[(size_t)gr * S + gc] : SENT;
    }
}

// ---------------------------------------------------------------------------
// K1: L0 band kernel. grid = 8 * 64 bands * 16 tiles = 8192, block 256.
// Produces h0 (512^2), x (256^2), p1 (128^2), p2 (64^2).
// ---------------------------------------------------------------------------
__global__ __launch_bounds__(256) void k_band_l0(
    const float* __restrict__ xin,
    const float* __restrict__ swsc, const float* __restrict__ sb,
    const float* __restrict__ ctxw, const float* __restrict__ ctxb,
    const float* __restrict__ bng, const float* __restrict__ bnb,
    const float* __restrict__ p1w, const float* __restrict__ p1b,
    const float* __restrict__ p2w, const float* __restrict__ p2b,
    float* __restrict__ outX, float* __restrict__ outH0,
    float* __restrict__ outP1, float* __restrict__ outP2)
{
    __shared__ float sx[3 * BCH];
    __shared__ float sxo[3][4][16];
    __shared__ float sp1[3][2][8];
    __shared__ float cw[81], cb[3], cinv[3], cbb[3];
    __shared__ float swt[144], ssb[3];
    __shared__ float w1[36], b1[3], w2[36], b2[3];

    int t = threadIdx.x, bid = blockIdx.x;
    int tileX = bid & 15, bandY = (bid >> 4) & 63, b = bid >> 10;

    if (t < 81)  cw[t]  = ctxw[t];
    if (t < 144) swt[t] = swsc[t];
    if (t < 36)  { w1[t] = p1w[t]; w2[t] = p2w[t]; }
    if (t < 3) {
        cb[t] = ctxb[t]; cinv[t] = bng[t] / sqrtf(1.001f); cbb[t] = bnb[t];
        ssb[t] = sb[t]; b1[t] = p1b[t]; b2[t] = p2b[t];
    }

    int gr0 = bandY * 16 - 1;
    int gc0 = tileX * 64;
    for (int c = 0; c < 3; c++)
        stage_band(xin + ((size_t)(b * 3 + c) << 20), &sx[c * BCH], gr0, gc0, 1024, t);
    __syncthreads();

    // ---- ctx L0: 32x8 outputs, 1/thread ----
    {
        int ox = t & 31, oy = t >> 5;
        float a0 = cb[0], a1 = cb[1], a2 = cb[2];
        #pragma unroll
        for (int c = 0; c < 3; c++) {
            float inv = cinv[c], bb = cbb[c];
            const float* L = &sx[c * BCH];
            #pragma unroll
            for (int kh = 0; kh < 3; kh++) {
                #pragma unroll
                for (int kw = 0; kw < 3; kw++) {
                    float v = L[(2 * oy + kh) * BSTR + 2 * ox + kw];
                    v = fmaxf(fmaf(inv, v, bb), 0.0f);
                    int wi = c * 9 + kh * 3 + kw;
                    a0 += cw[wi] * v; a1 += cw[27 + wi] * v; a2 += cw[54 + wi] * v;
                }
            }
        }
        size_t o = ((size_t)(b * 3)) * 262144 + (size_t)(bandY * 8 + oy) * 512 + tileX * 32 + ox;
        outH0[o] = a0; outH0[o + 262144] = a1; outH0[o + 524288] = a2;
    }

    // ---- sample conv: 16x4 outputs on threads 0..63 ----
    if (t < 64) {
        int xl = t & 15, yl = t >> 4;
        float s0 = 0.f, s1 = 0.f, s2 = 0.f;
        #pragma unroll
        for (int c = 0; c < 3; c++) {
            const float* L = &sx[c * BCH];
            #pragma unroll
            for (int kh = 0; kh < 4; kh++) {
                const float* r  = &L[(1 + 4 * yl + kh) * BSTR + 1 + 4 * xl];
                const float* w0 = &swt[(0 * 3 + c) * 16 + kh * 4];
                const float* w1p= &swt[(1 * 3 + c) * 16 + kh * 4];
                const float* w2p= &swt[(2 * 3 + c) * 16 + kh * 4];
                #pragma unroll
                for (int kw = 0; kw < 4; kw++) {
                    float v = r[kw];
                    s0 += w0[kw] * v; s1 += w1p[kw] * v; s2 += w2p[kw] * v;
                }
            }
        }
        float x0 = s0 + ssb[0], x1 = s1 + ssb[1], x2 = s2 + ssb[2];
        size_t o = ((size_t)(b * 3)) * 65536 + (size_t)(bandY * 4 + yl) * 256 + tileX * 16 + xl;
        outX[o] = x0; outX[o + 65536] = x1; outX[o + 131072] = x2;
        sxo[0][yl][xl] = x0; sxo[1][yl][xl] = x1; sxo[2][yl][xl] = x2;
    }
    __syncthreads();

    // ---- pool1: 8x2 outputs on threads 0..15 ----
    if (t < 16) {
        int px = t & 7, py = t >> 3;
        float a0 = b1[0], a1 = b1[1], a2 = b1[2];
        #pragma unroll
        for (int c = 0; c < 3; c++)
            #pragma unroll
            for (int kh = 0; kh < 2; kh++)
                #pragma unroll
                for (int kw = 0; kw < 2; kw++) {
                    float v = sxo[c][2 * py + kh][2 * px + kw];
                    int wi = c * 4 + kh * 2 + kw;
                    a0 += w1[wi] * v; a1 += w1[12 + wi] * v; a2 += w1[24 + wi] * v;
                }
        size_t o = ((size_t)(b * 3)) * 16384 + (size_t)(bandY * 2 + py) * 128 + tileX * 8 + px;
        outP1[o] = a0; outP1[o + 16384] = a1; outP1[o + 32768] = a2;
        sp1[0][py][px] = a0; sp1[1][py][px] = a1; sp1[2][py][px] = a2;
    }
    __syncthreads();

    // ---- pool2: 4x1 outputs on threads 0..3 ----
    if (t < 4) {
        int px = t;
        float a0 = b2[0], a1 = b2[1], a2 = b2[2];
        #pragma unroll
        for (int c = 0; c < 3; c++)
            #pragma unroll
            for (int kh = 0; kh < 2; kh++)
                #pragma unroll
                for (int kw = 0; kw < 2; kw++) {
                    float v = sp1[c][kh][2 * px + kw];
                    int wi = c * 4 + kh * 2 + kw;
                    a0 += w2[wi] * v; a1 += w2[12 + wi] * v; a2 += w2[24 + wi] * v;
                }
        size_t o = ((size_t)(b * 3)) * 4096 + (size_t)bandY * 64 + tileX * 4 + px;
        outP2[o] = a0; outP2[o + 4096] = a1; outP2[o + 8192] = a2;
    }
}

// ---------------------------------------------------------------------------
// K2: band ctx conv (L1..L3). grid = 8 * (S/16) * (S/64) blocks.
// ---------------------------------------------------------------------------
__global__ __launch_bounds__(256) void k_band_ctx(
    const float* __restrict__ in, float* __restrict__ outH, float* __restrict__ outF,
    const float* __restrict__ w, const float* __restrict__ bias,
    const float* __restrict__ bng, const float* __restrict__ bnb,
    int S, int tpxbits, int bandbits)
{
    __shared__ float sx[3 * BCH];
    __shared__ float cw[81], cb[3], cinv[3], cbb[3];
    int t = threadIdx.x, bid = blockIdx.x;
    int tileX = bid & ((1 << tpxbits) - 1);
    int bandY = (bid >> tpxbits) & ((1 << bandbits) - 1);
    int b = bid >> (tpxbits + bandbits);

    if (t < 81) cw[t] = w[t];
    if (t < 3) { cb[t] = bias[t]; cinv[t] = bng[t] / sqrtf(1.001f); cbb[t] = bnb[t]; }

    int gr0 = bandY * 16 - 1;
    int gc0 = tileX * 64;
    for (int c = 0; c < 3; c++)
        stage_band(in + (size_t)(b * 3 + c) * S * S, &sx[c * BCH], gr0, gc0, S, t);
    __syncthreads();

    int So = S >> 1;
    size_t os = (size_t)So * So;
    int ox = t & 31, oy = t >> 5;
    float a0 = cb[0], a1 = cb[1], a2 = cb[2];
    #pragma unroll
    for (int c = 0; c < 3; c++) {
        float inv = cinv[c], bb = cbb[c];
        const float* L = &sx[c * BCH];
        #pragma unroll
        for (int kh = 0; kh < 3; kh++) {
            #pragma unroll
            for (int kw = 0; kw < 3; kw++) {
                float v = L[(2 * oy + kh) * BSTR + 2 * ox + kw];
                v = fmaxf(fmaf(inv, v, bb), 0.0f);
                int wi = c * 9 + kh * 3 + kw;
                a0 += cw[wi] * v; a1 += cw[27 + wi] * v; a2 += cw[54 + wi] * v;
            }
        }
    }
    size_t o = (size_t)(b * 3) * os + (size_t)(bandY * 8 + oy) * So + tileX * 32 + ox;
    if (outH) { outH[o] = a0; outH[o + os] = a1; outH[o + 2 * os] = a2; }
    if (outF) { outF[o] = featf(a0); outF[o + os] = featf(a1); outF[o + 2 * os] = featf(a2); }
}

// ---------------------------------------------------------------------------
// K3: final select + soft VQ + cond counts + all 3 histograms (ballot-based)
// ---------------------------------------------------------------------------
__device__ __forceinline__ int argmin8(float v, const float* sc) {
    float best = 1e30f; int ki = 0;
    #pragma unroll
    for (int k = 0; k < 8; k++) {
        float df = v - sc[k]; float dk = df * df;
        if (dk < best) { best = dk; ki = k; }
    }
    return ki;
}

__global__ __launch_bounds__(256) void k_final(
    const float* __restrict__ x, const float* __restrict__ f1,
    const float* __restrict__ f2, const float* __restrict__ p1,
    const float* __restrict__ p2, const float* __restrict__ thresh,
    const float* __restrict__ centers, float* __restrict__ out,
    int* __restrict__ acc)
{
    __shared__ float sc[8];
    __shared__ int sh[11];
    int t = threadIdx.x;
    if (t < 8) sc[t] = centers[t];
    if (t < 11) sh[t] = 0;
    __syncthreads();
    float th1 = thresh[0], th2 = thresh[1];
    int gid = blockIdx.x * 256 + t;
    int xc = gid & 255, y = (gid >> 8) & 255, b = gid >> 16;
    int i2 = ((y >> 1) << 7) + (xc >> 1);
    int i4 = ((y >> 2) << 6) + (xc >> 2);
    int lane = t & 63;
    bool doM1 = ((y & 1) == 0) && ((xc & 1) == 0);
    bool doM2 = ((y & 3) == 0) && ((xc & 3) == 0);
    int c0n = 0, c1n = 0, c2n = 0;

    for (int c = 0; c < 3; c++) {
        int pc = b * 3 + c;
        float f1v = f1[(size_t)pc * 16384 + i2];
        float f2v = f2[(size_t)pc * 4096 + i4];
        float p1v = p1[(size_t)pc * 16384 + i2];
        float p2v = p2[(size_t)pc * 4096 + i4];
        float xv  = x[(size_t)pc * 65536 + (y << 8) + xc];
        bool cond2 = f2v < th2;
        bool cond1 = (!cond2) && (f1v < th1);
        bool cond0 = !(cond1 || cond2);
        float xq = cond2 ? p2v : (cond1 ? p1v : xv);

        float d[8]; float dmin = 1e30f;
        #pragma unroll
        for (int k = 0; k < 8; k++) { float df = xq - sc[k]; d[k] = df * df; dmin = fminf(dmin, d[k]); }
        float se = 0.f, sn = 0.f;
        #pragma unroll
        for (int k = 0; k < 8; k++) { float e = __expf(dmin - d[k]); se += e; sn += sc[k] * e; }
        out[(size_t)pc * 65536 + (y << 8) + xc] = sn / se;

        c0n += cond0; c1n += cond1; c2n += cond2;

        int k0 = argmin8(xv, sc);
        int k1 = argmin8(p1v, sc);
        int k2 = argmin8(p2v, sc);
        bool h0p = cond0;
        bool h1p = doM1 && (f2v >= th2) && (f1v < th1);
        bool h2p = doM2 && cond2;
        #pragma unroll
        for (int k = 0; k < 8; k++) {
            unsigned long long m0 = __ballot(h0p && (k0 == k));
            unsigned long long m1 = __ballot(h1p && (k1 == k));
            unsigned long long m2 = __ballot(h2p && (k2 == k));
            if (lane == 0) {
                int add = (int)(__popcll(m0) + __popcll(m1) + __popcll(m2));
                if (add) atomicAdd(&sh[k], add);
            }
        }
    }
    for (int off = 32; off > 0; off >>= 1) {
        c0n += __shfl_down(c0n, off);
        c1n += __shfl_down(c1n, off);
        c2n += __shfl_down(c2n, off);
    }
    if (lane == 0) { atomicAdd(&sh[8], c0n); atomicAdd(&sh[9], c1n); atomicAdd(&sh[10], c2n); }
    __syncthreads();
    if (t < 11) { int v = sh[t]; if (v) atomicAdd(&acc[t], v); }
}

// K4: finalize scalars
__global__ void k_finalize(const int* __restrict__ acc, float* __restrict__ out2) {
    if (threadIdx.x != 0 || blockIdx.x != 0) return;
    float cnt0 = (float)acc[8], cnt1 = (float)acc[9], cnt2 = (float)acc[10];
    float esti = cnt0 + cnt1 / 4.0f + cnt2 / 16.0f;
    float cr = (1.0f / 16.0f) * esti / (256.0f * 256.0f * 3.0f * 8.0f);
    float cs[8];
    float tot = 0.0f;
    for (int k = 0; k < 8; k++) { cs[k] = (float)acc[k]; tot += cs[k]; }
    float mean = 0.0f;
    for (int k = 0; k < 8; k++) { cs[k] /= tot; mean += cs[k]; }
    mean /= 8.0f;
    float var = 0.0f;
    for (int k = 0; k < 8; k++) { float df = cs[k] - mean; var += df * df; }
    var /= 7.0f;
    out2[0] = cr;
    out2[1] = sqrtf(var);
}

extern "C" void kernel_launch(void* const* d_in, const int* in_sizes, int n_in,
                              void* d_out, int out_size, void* d_ws, size_t ws_size,
                              hipStream_t stream) {
    const float* x_init   = (const float*)d_in[0];
    const float* thresh   = (const float*)d_in[1];
    const float* sample_w = (const float*)d_in[2];
    const float* sample_b = (const float*)d_in[3];
    const float* centers  = (const float*)d_in[4];
    const float* pool1_w  = (const float*)d_in[5];
    const float* pool1_b  = (const float*)d_in[6];
    const float* pool2_w  = (const float*)d_in[7];
    const float* pool2_b  = (const float*)d_in[8];
    const float* ctx_w    = (const float*)d_in[9];
    const float* ctx_b    = (const float*)d_in[10];
    const float* bn_g     = (const float*)d_in[11];
    const float* bn_b     = (const float*)d_in[12];
    float* out = (float*)d_out;

    float* wsf      = (float*)d_ws;
    float* w_scaled = wsf;
    int*   acc      = (int*)(wsf + 256);
    float* bufX     = wsf + 512;               // [8,3,256,256]
    float* bufH0    = bufX  + 1572864;         // [8,3,512,512]
    float* bufH1    = bufH0 + 6291456;         // [8,3,256,256]
    float* bufH2    = bufH1 + 1572864;         // [8,3,128,128]
    float* bufP1    = bufH2 + 393216;          // [8,3,128,128]
    float* bufP2    = bufP1 + 393216;          // [8,3,64,64]
    float* bufF1    = bufP2 + 98304;           // [8,3,128,128]
    float* bufF2    = bufF1 + 393216;          // [8,3,64,64]

    k_sigma_scale<<<1, 64, 0, stream>>>(sample_w, w_scaled, acc);
    k_band_l0<<<8192, 256, 0, stream>>>(x_init, w_scaled, sample_b,
                                        ctx_w, ctx_b, bn_g, bn_b,
                                        pool1_w, pool1_b, pool2_w, pool2_b,
                                        bufX, bufH0, bufP1, bufP2);
    // L1: S=512 -> 8 tilesX (3 bits), 32 bands (5 bits), 8 b => 2048 blocks
    k_band_ctx<<<2048, 256, 0, stream>>>(bufH0, bufH1, nullptr,
                                         ctx_w + 81,  ctx_b + 3, bn_g + 3, bn_b + 3,
                                         512, 3, 5);
    // L2: S=256 -> 4 tilesX (2 bits), 16 bands (4 bits) => 512 blocks
    k_band_ctx<<<512, 256, 0, stream>>>(bufH1, bufH2, bufF1,
                                        ctx_w + 162, ctx_b + 6, bn_g + 6, bn_b + 6,
                                        256, 2, 4);
    // L3: S=128 -> 2 tilesX (1 bit), 8 bands (3 bits) => 128 blocks
    k_band_ctx<<<128, 256, 0, stream>>>(bufH2, nullptr, bufF2,
                                        ctx_w + 243, ctx_b + 9, bn_g + 9, bn_b + 9,
                                        128, 1, 3);
    k_final<<<2048, 256, 0, stream>>>(bufX, bufF1, bufF2, bufP1, bufP2,
                                      thresh, centers, out, acc);
    k_finalize<<<1, 1, 0, stream>>>(acc, out + 1572864);
}